// Round 14
// baseline (480.360 us; speedup 1.0000x reference)
//
#include <hip/hip_runtime.h>

#define BB 32
#define TT 8
#define NN 1024
#define KNN 20
#define HH 64
#define CLS 14

__device__ __constant__ float kEPS = 1e-5f;

// order-preserving flip: float bits -> uint with same total order
__device__ __forceinline__ unsigned flipbits(unsigned u) {
    return u ^ ((unsigned)((int)u >> 31) | 0x80000000u);
}
// inverse of flipbits
__device__ __forceinline__ float unflip(unsigned fu) {
    const unsigned u = (fu & 0x80000000u) ? (fu ^ 0x80000000u) : ~fu;
    return __uint_as_float(u);
}
__device__ __forceinline__ int mbcnt64(unsigned long long m) {
    return (int)__builtin_amdgcn_mbcnt_hi((unsigned)(m >> 32),
            __builtin_amdgcn_mbcnt_lo((unsigned)m, 0u));
}

// Exact iterative extraction fallback (survivor-buffer overflow only; cold).
// Flips d[] to ordered-uint IN PLACE (no second array -> no extra VGPRs).
__device__ __forceinline__ void fallback20_f(float d[16], int lane, unsigned* nb) {
    #pragma unroll
    for (int i = 0; i < 16; ++i)
        d[i] = __uint_as_float(flipbits(__float_as_uint(d[i])));
    for (int kk = 0; kk < KNN; ++kk) {
        unsigned bv = __float_as_uint(d[0]);
        int bi = 0;
        #pragma unroll
        for (int i = 1; i < 16; ++i) {
            const unsigned v = __float_as_uint(d[i]);
            if (v < bv) { bv = v; bi = i; }
        }
        unsigned bj = (unsigned)(bi * 64 + lane);
        #pragma unroll
        for (int off = 32; off >= 1; off >>= 1) {
            const unsigned ov = __shfl_xor(bv, off, 64);
            const unsigned oj = __shfl_xor(bj, off, 64);
            if (ov < bv || (ov == bv && oj < bj)) { bv = ov; bj = oj; }
        }
        if (lane == 0) nb[kk] = bj;
        #pragma unroll
        for (int i = 0; i < 16; ++i)
            if (bj == (unsigned)(i * 64 + lane)) d[i] = __uint_as_float(0xFFFFFFFFu);
    }
}

// ---------------------------------------------------------------------------
// Kernel A — R11 structure (proven 213 us) + two register/latency cuts:
//  (a) per-lane MLP constants in LDS, read AFTER selection; epilogue re-reads
//      g1/be1 from global (R8-proven: kills the spill-driving live range)
//  (b) rank-by-counting via v_readlane over lanes instead of the LDS
//      broadcast loop: after compaction lane j's key IS key[j], so
//      rank = sum_j (readlane(key, j) < mykey) — no LDS reads, no load
//      latency chain, strictly less live state.
// Per point: float distances (16 pipelined ds_read_b128) -> per-lane min ->
// 12-step XOR-prefix ballot radix -> UB >= d(20) -> ballot-compact survivors
// (key = (flipped_fd<<32)|idx; u64 order == jax (dist, lowest-idx) order) ->
// exact top-20 by readlane rank -> EdgeConv with deferred ReLU/BN
// (sign-corrected weights, zmax only) -> relu/scale/bias/clamp once at end;
// uint atomicMax into acc. launch_bounds(256,4): the 64-VGPR cliff rules.
// ---------------------------------------------------------------------------
__global__ __launch_bounds__(256, 4) void knn_edge_kernel(
    const float* __restrict__ x,    // [B,T,N,3]
    const float* __restrict__ W1,   // [6,H]
    const float* __restrict__ b1,   // [H]
    const float* __restrict__ g1,   // [H]
    const float* __restrict__ be1,  // [H]
    float* __restrict__ acc)        // [B, 7*H], zero-initialized
{
    __shared__ float4 pts[NN];                      // x, y, z, |p|^2
    __shared__ unsigned long long keybuf[4][64];    // per-wave survivor keys
    __shared__ unsigned nbuf[4][KNN];               // per-wave neighbor indices
    __shared__ unsigned smax[HH];
    __shared__ float4 cstA[HH];                     // w03, w14, w25, sgn
    __shared__ float4 cstB[HH];                     // w3,  w4,  w5,  b1l

    const int chunk = blockIdx.x;   // 0..15
    const int b     = blockIdx.y;   // 0..31
    const int t     = blockIdx.z;   // 0..6

    const int tid  = threadIdx.x;
    const int lane = tid & 63;
    const int wave = tid >> 6;

    for (int i = tid; i < NN; i += 256) {
        const float* p = x + (((size_t)b * TT + t) * NN + i) * 3;
        const float px = p[0], py = p[1], pz = p[2];
        pts[i] = make_float4(px, py, pz, px * px + py * py + pz * pz);
    }
    if (tid < HH) {
        smax[tid] = 0u;
        const float w0 = W1[0 * HH + tid], w1 = W1[1 * HH + tid],
                    w2 = W1[2 * HH + tid], w3 = W1[3 * HH + tid],
                    w4 = W1[4 * HH + tid], w5 = W1[5 * HH + tid];
        const float scale = g1[tid] / sqrtf(1.0f + kEPS);
        const float sgn = (scale >= 0.0f) ? 1.0f : -1.0f;
        cstA[tid] = make_float4(sgn * (w0 - w3), sgn * (w1 - w4), sgn * (w2 - w5), sgn);
        cstB[tid] = make_float4(w3, w4, w5, b1[tid]);
    }
    __syncthreads();

    float zmax = -3.0e38f;   // max over edges of sign-corrected pre-activation

    const int n0 = chunk * 64 + wave * 16;
    for (int p = 0; p < 16; ++p) {
        const int n = n0 + p;
        const float* c = x + (((size_t)b * TT + (t + 1)) * NN + n) * 3;
        const float cx = c[0], cy = c[1], cz = c[2];   // wave-uniform -> SGPR
        const float s1 = cx * cx + cy * cy + cz * cz;
        const float n2x = -2.0f * cx, n2y = -2.0f * cy, n2z = -2.0f * cz;

        // float distances + per-lane min (fully unrolled -> pipelined ds_reads)
        float d[16];
        float mnf = 3.0e38f;
        #pragma unroll
        for (int i = 0; i < 16; ++i) {
            const float4 q = pts[i * 64 + lane];
            d[i] = fmaf(n2x, q.x, fmaf(n2y, q.y, fmaf(n2z, q.z, s1 + q.w)));
            mnf = fminf(mnf, d[i]);
        }
        const unsigned mn = flipbits(__float_as_uint(mnf));

        // 12-step ballot radix on lane-mins: UB >= 20th lane-min >= d(20)
        unsigned pp = 0;
        int krem = 19;
        #pragma unroll
        for (int bit = 31; bit >= 20; --bit) {
            const unsigned long long z = __ballot(((mn ^ pp) >> bit) == 0u);
            const int c0 = (int)__popcll(z);
            if (krem >= c0) { pp |= (1u << bit); krem -= c0; }
        }
        const float ubf = unflip(pp | 0xFFFFFu);   // finite (prefix of a real distance)

        // ballot-compact survivors (d <= ubf); key = (flipped_fd<<32)|idx so
        // u64 order == jax (distance, lowest-index) lexicographic order
        int base = 0;
        #pragma unroll
        for (int i = 0; i < 16; ++i) {
            const bool pr = d[i] <= ubf;
            const unsigned long long mk = __ballot(pr);
            if (pr) {
                const int pos = base + mbcnt64(mk);
                if (pos < 64) keybuf[wave][pos] =
                    ((unsigned long long)flipbits(__float_as_uint(d[i])) << 32)
                    | (unsigned)(i * 64 + lane);
            }
            base += (int)__popcll(mk);
        }

        if (base <= 64) {
            // exact top-20 by rank-by-counting, readlane edition: lane j's
            // loaded key IS key[j], so readlane supplies every key with no
            // LDS traffic and no load-latency chain.
            const unsigned long long mykey = keybuf[wave][lane];
            const unsigned mylo = (unsigned)mykey;
            const unsigned myhi = (unsigned)(mykey >> 32);
            int rank = 0;
            for (int j = 0; j < base; ++j) {       // wave-uniform trip count
                const unsigned klo = __builtin_amdgcn_readlane(mylo, j);
                const unsigned khi = __builtin_amdgcn_readlane(myhi, j);
                const unsigned long long kj =
                    ((unsigned long long)khi << 32) | klo;
                rank += (kj < mykey) ? 1 : 0;
            }
            if (lane < base && rank < KNN)
                nbuf[wave][rank] = (unsigned)mykey & 1023u;
        } else {
            fallback20_f(d, lane, &nbuf[wave][0]);   // cold; in-place flip
        }

        // EdgeConv, lane = channel, relu/BN deferred. Constants from LDS
        // (loaded AFTER selection so they never overlap d[16]'s live range).
        const float4 ca = cstA[lane];   // w03, w14, w25, sgn
        const float4 cb = cstB[lane];   // w3,  w4,  w5,  b1l
        const float mb = ca.w * fmaf(cx, cb.x, fmaf(cy, cb.y, fmaf(cz, cb.z, cb.w)));
        #pragma unroll
        for (int kk = 0; kk < KNN; ++kk) {
            const int j = (int)nbuf[wave][kk];     // uniform -> LDS broadcast
            const float4 q = pts[j];
            const float z = fmaf(q.x, ca.x, fmaf(q.y, ca.y, fmaf(q.z, ca.z, mb)));
            zmax = fmaxf(zmax, z);
        }
    }

    // epilogue: re-read channel constants (cold), undo sign, relu, BN, clamp
    {
        const float scale = g1[lane] / sqrtf(1.0f + kEPS);
        const float sgn = (scale >= 0.0f) ? 1.0f : -1.0f;
        const float r  = fmaxf(sgn * zmax, 0.0f);
        const float h  = fmaf(r, scale, be1[lane]);
        const float cm = fmaxf(h, 0.0f);
        atomicMax(&smax[lane], __float_as_uint(cm));
    }
    __syncthreads();
    if (tid < HH) {
        unsigned* dst = (unsigned*)(acc + ((size_t)b * 448 + t * 64 + tid));
        atomicMax(dst, smax[tid]);
    }
}

// ---------------------------------------------------------------------------
// Kernel B: MLP head, one block (512 threads) per batch row.
// ---------------------------------------------------------------------------
__global__ __launch_bounds__(512) void head_kernel(
    const float* __restrict__ acc,  // [B,448]
    const float* __restrict__ Wa, const float* __restrict__ ba,
    const float* __restrict__ ga, const float* __restrict__ bea,
    const float* __restrict__ Wb, const float* __restrict__ bb,
    const float* __restrict__ gb, const float* __restrict__ beb,
    const float* __restrict__ Wc, const float* __restrict__ bc,
    float* __restrict__ out)        // [B,CLS]
{
    __shared__ float s0[448];
    __shared__ float h1[512];
    __shared__ float h2[256];
    __shared__ float lg[CLS];
    __shared__ float red[2];

    const int b   = blockIdx.x;
    const int tid = threadIdx.x;
    const float inv = 1.0f / sqrtf(1.0f + kEPS);

    if (tid < 448) s0[tid] = acc[(size_t)b * 448 + tid];
    __syncthreads();

    {   // layer a: 448 -> 512
        float s = ba[tid];
        for (int d = 0; d < 448; ++d) s = fmaf(s0[d], Wa[d * 512 + tid], s);
        s = fmaxf(s, 0.0f);
        h1[tid] = fmaf(s, ga[tid] * inv, bea[tid]);
    }
    __syncthreads();
    if (tid < 256) {  // layer b: 512 -> 256
        float s = bb[tid];
        for (int d = 0; d < 512; ++d) s = fmaf(h1[d], Wb[d * 256 + tid], s);
        s = fmaxf(s, 0.0f);
        h2[tid] = fmaf(s, gb[tid] * inv, beb[tid]);
    }
    __syncthreads();
    if (tid < CLS) {  // logits: 256 -> 14
        float s = bc[tid];
        for (int d = 0; d < 256; ++d) s = fmaf(h2[d], Wc[d * CLS + tid], s);
        lg[tid] = s;
    }
    __syncthreads();
    if (tid == 0) {   // log_softmax over 14 classes
        float m = lg[0];
        for (int j = 1; j < CLS; ++j) m = fmaxf(m, lg[j]);
        float ssum = 0.0f;
        for (int j = 0; j < CLS; ++j) ssum += expf(lg[j] - m);
        red[0] = m;
        red[1] = logf(ssum);
    }
    __syncthreads();
    if (tid < CLS) out[(size_t)b * CLS + tid] = lg[tid] - red[0] - red[1];
}

extern "C" void kernel_launch(void* const* d_in, const int* in_sizes, int n_in,
                              void* d_out, int out_size, void* d_ws, size_t ws_size,
                              hipStream_t stream) {
    const float* x   = (const float*)d_in[0];
    // d_in[1] = batch (int64) — unused by the computation
    const float* W1  = (const float*)d_in[2];
    const float* b1  = (const float*)d_in[3];
    const float* g1  = (const float*)d_in[4];
    const float* be1 = (const float*)d_in[5];
    const float* Wa  = (const float*)d_in[6];
    const float* ba  = (const float*)d_in[7];
    const float* ga  = (const float*)d_in[8];
    const float* bea = (const float*)d_in[9];
    const float* Wb  = (const float*)d_in[10];
    const float* bb  = (const float*)d_in[11];
    const float* gb  = (const float*)d_in[12];
    const float* beb = (const float*)d_in[13];
    const float* Wc  = (const float*)d_in[14];
    const float* bc  = (const float*)d_in[15];
    float* out = (float*)d_out;
    float* acc = (float*)d_ws;      // [B,448] accumulator

    hipMemsetAsync(acc, 0, (size_t)BB * 448 * sizeof(float), stream);

    dim3 grid(16, BB, 7);
    knn_edge_kernel<<<grid, 256, 0, stream>>>(x, W1, b1, g1, be1, acc);
    head_kernel<<<BB, 512, 0, stream>>>(acc, Wa, ba, ga, bea,
                                        Wb, bb, gb, beb, Wc, bc, out);
}

// Round 15
// 232.982 us; speedup vs baseline: 2.0618x; 2.0618x over previous
//
#include <hip/hip_runtime.h>

#define BB 32
#define TT 8
#define NN 1024
#define KNN 20
#define HH 64
#define CLS 14

__device__ __constant__ float kEPS = 1e-5f;

// order-preserving flip: float bits -> uint with same total order
__device__ __forceinline__ unsigned flipbits(unsigned u) {
    return u ^ ((unsigned)((int)u >> 31) | 0x80000000u);
}
// inverse of flipbits
__device__ __forceinline__ float unflip(unsigned fu) {
    const unsigned u = (fu & 0x80000000u) ? (fu ^ 0x80000000u) : ~fu;
    return __uint_as_float(u);
}
__device__ __forceinline__ int mbcnt64(unsigned long long m) {
    return (int)__builtin_amdgcn_mbcnt_hi((unsigned)(m >> 32),
            __builtin_amdgcn_mbcnt_lo((unsigned)m, 0u));
}

// Exact iterative extraction fallback (survivor-buffer overflow only; cold).
__device__ __forceinline__ void fallback20(unsigned fd[16], int lane, unsigned* nb) {
    for (int kk = 0; kk < KNN; ++kk) {
        unsigned bv = fd[0];
        int bi = 0;
        #pragma unroll
        for (int i = 1; i < 16; ++i)
            if (fd[i] < bv) { bv = fd[i]; bi = i; }
        unsigned bj = (unsigned)(bi * 64 + lane);
        #pragma unroll
        for (int off = 32; off >= 1; off >>= 1) {
            const unsigned ov = __shfl_xor(bv, off, 64);
            const unsigned oj = __shfl_xor(bj, off, 64);
            if (ov < bv || (ov == bv && oj < bj)) { bv = ov; bj = oj; }
        }
        if (lane == 0) nb[kk] = bj;
        #pragma unroll
        for (int i = 0; i < 16; ++i)
            if (bj == (unsigned)(i * 64 + lane)) fd[i] = 0xFFFFFFFFu;
    }
}

// ---------------------------------------------------------------------------
// Kernel A — the PROVEN R11 kernel (213.7 us knn, 234.8 us total), restored
// byte-identical after R12/R14 experiments regressed (allocator spill
// explosions at the 64-VGPR clamp). Structure:
// per (t, b, 64-point chunk); one wave = 16 query points, one at a time.
// Per point: float distances (16 pipelined ds_read_b128) -> per-lane min ->
// 12-step XOR-prefix ballot radix -> UB >= d(20) -> ballot-compact survivors
// (key = (flipped_fd<<32)|idx; u64 order == jax (dist, lowest-idx) order) ->
// exact top-20 via rank-by-counting over the survivor keys in LDS (each lane
// counts keys < its own; rank<20 -> nbuf[rank]=idx; keys distinct, base>=20
// guaranteed by the UB invariant) -> EdgeConv with deferred ReLU/BN
// (sign-corrected weights, zmax only) -> relu/scale/bias/clamp once per
// thread at the end; uint atomicMax into acc.
// launch_bounds(256,4): occupancy at the 64-VGPR cliff dominates everything
// (R4-R14 evidence); modest spills (~14 MB) are the accepted price.
// ---------------------------------------------------------------------------
__global__ __launch_bounds__(256, 4) void knn_edge_kernel(
    const float* __restrict__ x,    // [B,T,N,3]
    const float* __restrict__ W1,   // [6,H]
    const float* __restrict__ b1,   // [H]
    const float* __restrict__ g1,   // [H]
    const float* __restrict__ be1,  // [H]
    float* __restrict__ acc)        // [B, 7*H], zero-initialized
{
    __shared__ float4 pts[NN];                      // x, y, z, |p|^2
    __shared__ unsigned long long keybuf[4][64];    // per-wave survivor keys
    __shared__ unsigned nbuf[4][KNN];               // per-wave neighbor indices
    __shared__ unsigned smax[HH];

    const int chunk = blockIdx.x;   // 0..15
    const int b     = blockIdx.y;   // 0..31
    const int t     = blockIdx.z;   // 0..6

    const int tid  = threadIdx.x;
    const int lane = tid & 63;
    const int wave = tid >> 6;

    for (int i = tid; i < NN; i += 256) {
        const float* p = x + (((size_t)b * TT + t) * NN + i) * 3;
        const float px = p[0], py = p[1], pz = p[2];
        pts[i] = make_float4(px, py, pz, px * px + py * py + pz * pz);
    }
    if (tid < HH) smax[tid] = 0u;
    __syncthreads();

    const float w3 = W1[3 * HH + lane], w4 = W1[4 * HH + lane],
                w5 = W1[5 * HH + lane];
    const float b1l   = b1[lane];
    const float scale = g1[lane] / sqrtf(1.0f + kEPS);
    const float be1l  = be1[lane];
    const float sgn = (scale >= 0.0f) ? 1.0f : -1.0f;
    const float w03 = sgn * (W1[0 * HH + lane] - w3),
                w14 = sgn * (W1[1 * HH + lane] - w4),
                w25 = sgn * (W1[2 * HH + lane] - w5);

    float zmax = -3.0e38f;   // max over edges of sign-corrected pre-activation

    const int n0 = chunk * 64 + wave * 16;
    for (int p = 0; p < 16; ++p) {
        const int n = n0 + p;
        const float* c = x + (((size_t)b * TT + (t + 1)) * NN + n) * 3;
        const float cx = c[0], cy = c[1], cz = c[2];
        const float s1 = cx * cx + cy * cy + cz * cz;
        const float n2x = -2.0f * cx, n2y = -2.0f * cy, n2z = -2.0f * cz;

        // float distances + per-lane min (fully unrolled -> pipelined ds_reads)
        float d[16];
        float mnf = 3.0e38f;
        #pragma unroll
        for (int i = 0; i < 16; ++i) {
            const float4 q = pts[i * 64 + lane];
            d[i] = fmaf(n2x, q.x, fmaf(n2y, q.y, fmaf(n2z, q.z, s1 + q.w)));
            mnf = fminf(mnf, d[i]);
        }
        const unsigned mn = flipbits(__float_as_uint(mnf));

        // 12-step ballot radix on lane-mins: UB >= 20th lane-min >= d(20)
        unsigned pp = 0;
        int krem = 19;
        #pragma unroll
        for (int bit = 31; bit >= 20; --bit) {
            const unsigned long long z = __ballot(((mn ^ pp) >> bit) == 0u);
            const int c0 = (int)__popcll(z);
            if (krem >= c0) { pp |= (1u << bit); krem -= c0; }
        }
        const float ubf = unflip(pp | 0xFFFFFu);   // finite (prefix of a real distance)

        // ballot-compact survivors (d <= ubf); key = (flipped_fd<<32)|idx so
        // u64 order == jax (distance, lowest-index) lexicographic order
        int base = 0;
        #pragma unroll
        for (int i = 0; i < 16; ++i) {
            const bool pr = d[i] <= ubf;
            const unsigned long long mk = __ballot(pr);
            if (pr) {
                const int pos = base + mbcnt64(mk);
                if (pos < 64) keybuf[wave][pos] =
                    ((unsigned long long)flipbits(__float_as_uint(d[i])) << 32)
                    | (unsigned)(i * 64 + lane);
            }
            base += (int)__popcll(mk);
        }

        if (base <= 64) {
            // exact top-20 by rank-by-counting over survivor keys in LDS.
            const unsigned long long mykey = keybuf[wave][lane];
            int rank = 0;
            for (int j = 0; j < base; ++j) {        // wave-uniform trip count
                const unsigned long long kj = keybuf[wave][j];  // LDS broadcast
                rank += (kj < mykey) ? 1 : 0;
            }
            if (lane < base && rank < KNN)
                nbuf[wave][rank] = (unsigned)mykey & 1023u;
        } else {
            // cold path: flipped distances, exact iterative extraction
            unsigned fd[16];
            #pragma unroll
            for (int i = 0; i < 16; ++i) fd[i] = flipbits(__float_as_uint(d[i]));
            fallback20(fd, lane, &nbuf[wave][0]);
        }

        // EdgeConv, lane = channel, relu/BN deferred:
        // z = sgn * (b1 + c·(w3,w4,w5) + n·(w0-w3,w1-w4,w2-w5))
        const float mb = sgn * fmaf(cx, w3, fmaf(cy, w4, fmaf(cz, w5, b1l)));
        #pragma unroll
        for (int kk = 0; kk < KNN; ++kk) {
            const int j = (int)nbuf[wave][kk];     // uniform -> LDS broadcast
            const float4 q = pts[j];
            const float z = fmaf(q.x, w03, fmaf(q.y, w14, fmaf(q.z, w25, mb)));
            zmax = fmaxf(zmax, z);
        }
    }

    // epilogue: undo sign, apply relu, BN affine, clamp at 0
    const float r  = fmaxf(sgn * zmax, 0.0f);
    const float h  = fmaf(r, scale, be1l);
    const float cm = fmaxf(h, 0.0f);
    atomicMax(&smax[lane], __float_as_uint(cm));
    __syncthreads();
    if (tid < HH) {
        unsigned* dst = (unsigned*)(acc + ((size_t)b * 448 + t * 64 + tid));
        atomicMax(dst, smax[tid]);
    }
}

// ---------------------------------------------------------------------------
// Kernel B: MLP head, one block (512 threads) per batch row.
// ---------------------------------------------------------------------------
__global__ __launch_bounds__(512) void head_kernel(
    const float* __restrict__ acc,  // [B,448]
    const float* __restrict__ Wa, const float* __restrict__ ba,
    const float* __restrict__ ga, const float* __restrict__ bea,
    const float* __restrict__ Wb, const float* __restrict__ bb,
    const float* __restrict__ gb, const float* __restrict__ beb,
    const float* __restrict__ Wc, const float* __restrict__ bc,
    float* __restrict__ out)        // [B,CLS]
{
    __shared__ float s0[448];
    __shared__ float h1[512];
    __shared__ float h2[256];
    __shared__ float lg[CLS];
    __shared__ float red[2];

    const int b   = blockIdx.x;
    const int tid = threadIdx.x;
    const float inv = 1.0f / sqrtf(1.0f + kEPS);

    if (tid < 448) s0[tid] = acc[(size_t)b * 448 + tid];
    __syncthreads();

    {   // layer a: 448 -> 512
        float s = ba[tid];
        for (int d = 0; d < 448; ++d) s = fmaf(s0[d], Wa[d * 512 + tid], s);
        s = fmaxf(s, 0.0f);
        h1[tid] = fmaf(s, ga[tid] * inv, bea[tid]);
    }
    __syncthreads();
    if (tid < 256) {  // layer b: 512 -> 256
        float s = bb[tid];
        for (int d = 0; d < 512; ++d) s = fmaf(h1[d], Wb[d * 256 + tid], s);
        s = fmaxf(s, 0.0f);
        h2[tid] = fmaf(s, gb[tid] * inv, beb[tid]);
    }
    __syncthreads();
    if (tid < CLS) {  // logits: 256 -> 14
        float s = bc[tid];
        for (int d = 0; d < 256; ++d) s = fmaf(h2[d], Wc[d * CLS + tid], s);
        lg[tid] = s;
    }
    __syncthreads();
    if (tid == 0) {   // log_softmax over 14 classes
        float m = lg[0];
        for (int j = 1; j < CLS; ++j) m = fmaxf(m, lg[j]);
        float ssum = 0.0f;
        for (int j = 0; j < CLS; ++j) ssum += expf(lg[j] - m);
        red[0] = m;
        red[1] = logf(ssum);
    }
    __syncthreads();
    if (tid < CLS) out[(size_t)b * CLS + tid] = lg[tid] - red[0] - red[1];
}

extern "C" void kernel_launch(void* const* d_in, const int* in_sizes, int n_in,
                              void* d_out, int out_size, void* d_ws, size_t ws_size,
                              hipStream_t stream) {
    const float* x   = (const float*)d_in[0];
    // d_in[1] = batch (int64) — unused by the computation
    const float* W1  = (const float*)d_in[2];
    const float* b1  = (const float*)d_in[3];
    const float* g1  = (const float*)d_in[4];
    const float* be1 = (const float*)d_in[5];
    const float* Wa  = (const float*)d_in[6];
    const float* ba  = (const float*)d_in[7];
    const float* ga  = (const float*)d_in[8];
    const float* bea = (const float*)d_in[9];
    const float* Wb  = (const float*)d_in[10];
    const float* bb  = (const float*)d_in[11];
    const float* gb  = (const float*)d_in[12];
    const float* beb = (const float*)d_in[13];
    const float* Wc  = (const float*)d_in[14];
    const float* bc  = (const float*)d_in[15];
    float* out = (float*)d_out;
    float* acc = (float*)d_ws;      // [B,448] accumulator

    hipMemsetAsync(acc, 0, (size_t)BB * 448 * sizeof(float), stream);

    dim3 grid(16, BB, 7);
    knn_edge_kernel<<<grid, 256, 0, stream>>>(x, W1, b1, g1, be1, acc);
    head_kernel<<<BB, 512, 0, stream>>>(acc, Wa, ba, ga, bea,
                                        Wb, bb, gb, beb, Wc, bc, out);
}